// Round 6
// baseline (152.188 us; speedup 1.0000x reference)
//
#include <hip/hip_runtime.h>
#include <hip/hip_fp16.h>
#include <math.h>

typedef __attribute__((ext_vector_type(8))) _Float16 half8;
typedef __attribute__((ext_vector_type(4))) _Float16 half4;
typedef __attribute__((ext_vector_type(4))) float f32x4;

#define HQ 16
#define HK 4
#define DH 64
#define NB 2
#define SEQ 2048
#define EDIM 1024
#define KD 1024

// ---------------- prep: convert x to f16 ----------------
__global__ __launch_bounds__(256) void cvt_x_kernel(const float* __restrict__ x,
                                                    _Float16* __restrict__ xh, int n4) {
  int i = blockIdx.x * 256 + threadIdx.x;
  if (i >= n4) return;
  float4 v = ((const float4*)x)[i];
  half4 h;
  h[0] = (_Float16)v.x; h[1] = (_Float16)v.y; h[2] = (_Float16)v.z; h[3] = (_Float16)v.w;
  *(half4*)(xh + (size_t)i * 4) = h;
}

// ---------------- prep: RoPE sin/cos table [4096 rows][32 freqs] ----------------
__global__ __launch_bounds__(256) void rope_tab_kernel(const int* __restrict__ qpos,
                                                       float2* __restrict__ tab) {
  int i = blockIdx.x * 256 + threadIdx.x;   // 0 .. 4096*32-1
  int row = i >> 5, d = i & 31;
  float ang = (float)qpos[row] * expf((float)d * -0.2878231366242558f); // -ln(10000)/32
  float sn, cs;
  sincosf(ang, &sn, &cs);
  tab[i] = make_float2(sn, cs);
}

// ---------------- prep: W [K][N] f32 -> WT [N][K] f16 ----------------
__global__ __launch_bounds__(256) void transpose_w_kernel(const float* __restrict__ W,
                                                          _Float16* __restrict__ WT,
                                                          int N, int row_off) {
  __shared__ float t[64][65];
  int n0 = blockIdx.x * 64, k0 = blockIdx.y * 64;
  int tid = threadIdx.x;
#pragma unroll
  for (int p = 0; p < 4; ++p) {
    int idx = tid + p * 256;
    int r = idx >> 4;      // k row 0..63
    int c4 = idx & 15;     // float4 col
    float4 v = *(const float4*)(W + (size_t)(k0 + r) * N + n0 + c4 * 4);
    t[r][c4 * 4 + 0] = v.x; t[r][c4 * 4 + 1] = v.y;
    t[r][c4 * 4 + 2] = v.z; t[r][c4 * 4 + 3] = v.w;
  }
  __syncthreads();
#pragma unroll
  for (int p = 0; p < 4; ++p) {
    int idx = tid + p * 256;
    int n = idx >> 4;
    int k4 = idx & 15;
    half4 h;
    h[0] = (_Float16)t[k4 * 4 + 0][n]; h[1] = (_Float16)t[k4 * 4 + 1][n];
    h[2] = (_Float16)t[k4 * 4 + 2][n]; h[3] = (_Float16)t[k4 * 4 + 3][n];
    *(half4*)(WT + (size_t)(row_off + n0 + n) * KD + k0 + k4 * 4) = h;
  }
}

// ---------------- prep: V [bh][s][d] -> V^T [bh][d][s] ----------------
__global__ __launch_bounds__(256) void transpose_v_kernel(const _Float16* __restrict__ vhp,
                                                          _Float16* __restrict__ vtp) {
  __shared__ _Float16 t[64][72];
  int bh = blockIdx.y;           // 0..7  (b*HK+hk)
  int s0 = blockIdx.x * 64;      // 32 tiles over SEQ
  const _Float16* src = vhp + ((size_t)bh * SEQ + s0) * DH;
  _Float16* dst = vtp + (size_t)bh * DH * SEQ + s0;
  int tid = threadIdx.x;
#pragma unroll
  for (int p = 0; p < 2; ++p) {
    int idx = tid + p * 256;     // 512 half8s
    int r = idx >> 3, c8 = idx & 7;
    half8 v = *(const half8*)(src + (size_t)r * DH + c8 * 8);
#pragma unroll
    for (int i = 0; i < 8; ++i) t[r][c8 * 8 + i] = v[i];
  }
  __syncthreads();
#pragma unroll
  for (int p = 0; p < 2; ++p) {
    int idx = tid + p * 256;
    int d = idx >> 3, c8 = idx & 7;
    half8 v;
#pragma unroll
    for (int i = 0; i < 8; ++i) v[i] = t[c8 * 8 + i][d];
    *(half8*)(dst + (size_t)d * SEQ + c8 * 8) = v;
  }
}

// swizzle: XOR bits 4-6 of the byte offset with row&7 (row stride 128B tiles)
#define SWZ(r, kb) ((kb) ^ (((r) & 7) << 4))

// ---------------- K1: fused QKV GEMM + RoPE (table-driven) ----------------
// C[4096][1536] = xh[4096][1024] @ W; cols 0-1023 -> q, 1024-1279 -> k, 1280-1535 -> v
__global__ __launch_bounds__(256) void gemm_qkv_rope(
    const _Float16* __restrict__ xh, const _Float16* __restrict__ WT,
    const float2* __restrict__ rtab,
    _Float16* __restrict__ qh, _Float16* __restrict__ kh, _Float16* __restrict__ vh) {
  __shared__ char As[128 * 64 * 2];
  __shared__ char Bs[128 * 64 * 2];
  int tid = threadIdx.x, lane = tid & 63, wid = tid >> 6;
  int wr = wid >> 1, wc = wid & 1;
  int bm = blockIdx.x, bn = blockIdx.y;

  const _Float16* Ag = xh + (size_t)bm * 128 * KD;
  const _Float16* Bg = WT + (size_t)bn * 128 * KD;

  f32x4 acc[4][4] = {};

  for (int kt = 0; kt < KD / 64; ++kt) {
#pragma unroll
    for (int p = 0; p < 4; ++p) {
      int idx = tid + p * 256;
      int r = idx >> 3, k8 = idx & 7;
      half8 va = *(const half8*)(Ag + (size_t)r * KD + kt * 64 + k8 * 8);
      *(half8*)(As + r * 128 + SWZ(r, k8 * 16)) = va;
      half8 vb = *(const half8*)(Bg + (size_t)r * KD + kt * 64 + k8 * 8);
      *(half8*)(Bs + r * 128 + SWZ(r, k8 * 16)) = vb;
    }
    __syncthreads();
#pragma unroll
    for (int kk = 0; kk < 2; ++kk) {
      int kb = kk * 64 + (lane >> 4) * 16;
      half8 af[4], bf[4];
#pragma unroll
      for (int mf = 0; mf < 4; ++mf) {
        int r = wr * 64 + mf * 16 + (lane & 15);
        af[mf] = *(const half8*)(As + r * 128 + SWZ(r, kb));
      }
#pragma unroll
      for (int nf = 0; nf < 4; ++nf) {
        int r = wc * 64 + nf * 16 + (lane & 15);
        bf[nf] = *(const half8*)(Bs + r * 128 + SWZ(r, kb));
      }
#pragma unroll
      for (int mf = 0; mf < 4; ++mf)
#pragma unroll
        for (int nf = 0; nf < 4; ++nf)
          acc[mf][nf] = __builtin_amdgcn_mfma_f32_16x16x32_f16(af[mf], bf[nf], acc[mf][nf], 0, 0, 0);
    }
    __syncthreads();
  }

  // epilogue: wave covers 64 contiguous cols = exactly one head
  int col0 = bn * 128 + wc * 64;
  int row_base = bm * 128 + wr * 64;
#pragma unroll
  for (int mf = 0; mf < 4; ++mf) {
#pragma unroll
    for (int j = 0; j < 4; ++j) {
      int row = row_base + mf * 16 + (lane >> 4) * 4 + j;
      int b = row >> 11, s = row & (SEQ - 1);
      if (col0 < 1024) {
        int hq = col0 >> 6;
        size_t base = (((size_t)b * HQ + hq) * SEQ + s) * DH;
#pragma unroll
        for (int nf = 0; nf < 2; ++nf) {
          int d = nf * 16 + (lane & 15);  // 0..31
          float2 scv = rtab[row * 32 + d];
          float x1 = acc[mf][nf][j], x2 = acc[mf][nf + 2][j];
          qh[base + d]      = (_Float16)(x1 * scv.y - x2 * scv.x);
          qh[base + d + 32] = (_Float16)(x2 * scv.y + x1 * scv.x);
        }
      } else if (col0 < 1280) {
        int hk = (col0 - 1024) >> 6;
        size_t base = (((size_t)b * HK + hk) * SEQ + s) * DH;
#pragma unroll
        for (int nf = 0; nf < 2; ++nf) {
          int d = nf * 16 + (lane & 15);
          float2 scv = rtab[row * 32 + d];
          float x1 = acc[mf][nf][j], x2 = acc[mf][nf + 2][j];
          kh[base + d]      = (_Float16)(x1 * scv.y - x2 * scv.x);
          kh[base + d + 32] = (_Float16)(x2 * scv.y + x1 * scv.x);
        }
      } else {
        int hk = (col0 - 1280) >> 6;
        size_t base = (((size_t)b * HK + hk) * SEQ + s) * DH;
#pragma unroll
        for (int nf = 0; nf < 4; ++nf) {
          int d = nf * 16 + (lane & 15);
          vh[base + d] = (_Float16)acc[mf][nf][j];
        }
      }
    }
  }
}

// ---------------- K2: flash attention, swapped-QK^T, async-staged ----------------
// grid: (qt=16, bh=32). block 256 = 4 waves x 32 q-rows. KV tile = 128.
// V pre-transposed: vt[bh][d][s]. Q pre-scaled by log2e; exp -> exp2.
// T14: next tile global->regs issued before compute, regs->LDS after barrier.
// T13: defer-max with THR=8 (log2 domain). T5: setprio around MFMA clusters.
__global__ __launch_bounds__(256) void attn_kernel(
    const _Float16* __restrict__ qh, const _Float16* __restrict__ kh,
    const _Float16* __restrict__ vt, _Float16* __restrict__ oh) {
  __shared__ char Ks[128 * 64 * 2];      // 16KB [kv][d] swz, row 128B
  __shared__ char Vs[64 * 128 * 2];      // 16KB [d][kv] swz, row 256B
  __shared__ char Ps[4 * 32 * 64 * 2];   // 16KB per-wave [32 q][64 kv] swz, row 128B

  int tid = threadIdx.x, lane = tid & 63, wid = tid >> 6;
  int g = lane >> 4, qi = lane & 15;
  int qt = blockIdx.x;
  int bh = blockIdx.y;
  int b = bh >> 4, hq = bh & 15, hk = hq >> 2;

  const _Float16* Qg = qh + (((size_t)b * HQ + hq) * SEQ + qt * 128 + wid * 32) * DH;
  const _Float16* Kg = kh + (((size_t)b * HK + hk) * SEQ) * DH;
  const _Float16* Vtg = vt + (size_t)(b * HK + hk) * DH * SEQ;

  // staging addresses (fixed per thread)
  int kr = tid >> 3, kd8 = tid & 7;      // K: rows kr, kr+32, kr+64, kr+96
  int vr = tid >> 4, vc8 = tid & 15;     // V: rows vr, vr+16, vr+32, vr+48

  // Q fragments in registers, pre-scaled by log2(e)
  const _Float16 l2e = (_Float16)1.44269504f;
  half8 qf[2][2];
#pragma unroll
  for (int mf = 0; mf < 2; ++mf)
#pragma unroll
    for (int kk = 0; kk < 2; ++kk) {
      half8 q0 = *(const half8*)(Qg + (mf * 16 + qi) * DH + kk * 32 + g * 8);
#pragma unroll
      for (int i = 0; i < 8; ++i) q0[i] = q0[i] * l2e;
      qf[mf][kk] = q0;
    }

  f32x4 oacc[2][4] = {};
  float mrow[2] = {-3e38f, -3e38f};
  float lrow[2] = {0.f, 0.f};

  char* Pw = Ps + wid * (32 * 64 * 2);

  half8 kreg[4], vreg[4];
  // prologue: stage tile 0
#pragma unroll
  for (int p = 0; p < 4; ++p) {
    kreg[p] = *(const half8*)(Kg + (size_t)(kr + p * 32) * DH + kd8 * 8);
    vreg[p] = *(const half8*)(Vtg + (size_t)(vr + p * 16) * SEQ + vc8 * 8);
  }
#pragma unroll
  for (int p = 0; p < 4; ++p) {
    int r = kr + p * 32;
    *(half8*)(Ks + r * 128 + SWZ(r, kd8 * 16)) = kreg[p];
    int d = vr + p * 16;
    *(half8*)(Vs + d * 256 + SWZ(d, vc8 * 16)) = vreg[p];
  }
  __syncthreads();

  for (int kt = 0; kt < SEQ / 128; ++kt) {
    bool more = (kt + 1 < SEQ / 128);
    // T14: issue next tile's global loads now; latency hides under compute
    if (more) {
#pragma unroll
      for (int p = 0; p < 4; ++p) {
        kreg[p] = *(const half8*)(Kg + (size_t)((kt + 1) * 128 + kr + p * 32) * DH + kd8 * 8);
        vreg[p] = *(const half8*)(Vtg + (size_t)(vr + p * 16) * SEQ + (kt + 1) * 128 + vc8 * 8);
      }
    }

    // S^T = K Q^T : lane holds S[q=mf*16+qi][kv=nf*16+g*4+j]
    f32x4 sc[2][8] = {};
    __builtin_amdgcn_s_setprio(1);
#pragma unroll
    for (int nf = 0; nf < 8; ++nf) {
      int r = nf * 16 + qi;
      half8 kf0 = *(const half8*)(Ks + r * 128 + SWZ(r, g * 16));
      half8 kf1 = *(const half8*)(Ks + r * 128 + SWZ(r, g * 16 + 64));
#pragma unroll
      for (int mf = 0; mf < 2; ++mf) {
        sc[mf][nf] = __builtin_amdgcn_mfma_f32_16x16x32_f16(kf0, qf[mf][0], sc[mf][nf], 0, 0, 0);
        sc[mf][nf] = __builtin_amdgcn_mfma_f32_16x16x32_f16(kf1, qf[mf][1], sc[mf][nf], 0, 0, 0);
      }
    }
    __builtin_amdgcn_s_setprio(0);

    // online softmax max phase, with defer-max (THR=8 in log2 domain)
    float psum[2] = {0.f, 0.f};
#pragma unroll
    for (int mf = 0; mf < 2; ++mf) {
      float p0 = sc[mf][0][0], p1 = sc[mf][0][1], p2 = sc[mf][0][2], p3 = sc[mf][0][3];
#pragma unroll
      for (int nf = 1; nf < 8; ++nf) {
        p0 = fmaxf(p0, sc[mf][nf][0]); p1 = fmaxf(p1, sc[mf][nf][1]);
        p2 = fmaxf(p2, sc[mf][nf][2]); p3 = fmaxf(p3, sc[mf][nf][3]);
      }
      float pm = fmaxf(fmaxf(p0, p1), fmaxf(p2, p3));
      pm = fmaxf(pm, __shfl_xor(pm, 16, 64));
      pm = fmaxf(pm, __shfl_xor(pm, 32, 64));
      if (__any(pm > mrow[mf] + 8.f)) {
        float mnew = fmaxf(mrow[mf], pm);
        float alpha = __builtin_amdgcn_exp2f(mrow[mf] - mnew);
        mrow[mf] = mnew;
        lrow[mf] *= alpha;
#pragma unroll
        for (int nf2 = 0; nf2 < 4; ++nf2)
#pragma unroll
          for (int j = 0; j < 4; ++j) oacc[mf][nf2][j] *= alpha;
      }
    }

    // two kv-halves of 64: exp+pack+P-write, then PV (same-wave DS order => safe reuse)
#pragma unroll
    for (int h = 0; h < 2; ++h) {
#pragma unroll
      for (int mf = 0; mf < 2; ++mf) {
        int prow = mf * 16 + qi;
        char* pwr = Pw + prow * 128;
        int pswz = (prow & 7) << 4;
#pragma unroll
        for (int nfl = 0; nfl < 4; ++nfl) {
          int nf = h * 4 + nfl;
          float e0 = __builtin_amdgcn_exp2f(sc[mf][nf][0] - mrow[mf]);
          float e1 = __builtin_amdgcn_exp2f(sc[mf][nf][1] - mrow[mf]);
          float e2 = __builtin_amdgcn_exp2f(sc[mf][nf][2] - mrow[mf]);
          float e3 = __builtin_amdgcn_exp2f(sc[mf][nf][3] - mrow[mf]);
          psum[mf] += (e0 + e1) + (e2 + e3);
          uint2 w;
          w.x = __builtin_bit_cast(unsigned, __builtin_amdgcn_cvt_pkrtz(e0, e1));
          w.y = __builtin_bit_cast(unsigned, __builtin_amdgcn_cvt_pkrtz(e2, e3));
          *(uint2*)(pwr + ((nfl * 32 + g * 8) ^ pswz)) = w;
        }
      }
      __builtin_amdgcn_s_setprio(1);
#pragma unroll
      for (int tl = 0; tl < 2; ++tl) {
        half8 pb[2], vb[4];
#pragma unroll
        for (int mf = 0; mf < 2; ++mf) {
          int r = mf * 16 + qi;
          pb[mf] = *(const half8*)(Pw + r * 128 + SWZ(r, tl * 64 + g * 16));
        }
#pragma unroll
        for (int nf2 = 0; nf2 < 4; ++nf2) {
          int dd = nf2 * 16 + qi;
          vb[nf2] = *(const half8*)(Vs + dd * 256 + SWZ(dd, h * 128 + tl * 64 + g * 16));
        }
#pragma unroll
        for (int mf = 0; mf < 2; ++mf)
#pragma unroll
          for (int nf2 = 0; nf2 < 4; ++nf2)
            oacc[mf][nf2] = __builtin_amdgcn_mfma_f32_16x16x32_f16(vb[nf2], pb[mf], oacc[mf][nf2], 0, 0, 0);
      }
      __builtin_amdgcn_s_setprio(0);
    }

    // finish row sums
#pragma unroll
    for (int mf = 0; mf < 2; ++mf) {
      float s = psum[mf];
      s += __shfl_xor(s, 16, 64);
      s += __shfl_xor(s, 32, 64);
      lrow[mf] += s;
    }

    __syncthreads();
    if (more) {
#pragma unroll
      for (int p = 0; p < 4; ++p) {
        int r = kr + p * 32;
        *(half8*)(Ks + r * 128 + SWZ(r, kd8 * 16)) = kreg[p];
        int d = vr + p * 16;
        *(half8*)(Vs + d * 256 + SWZ(d, vc8 * 16)) = vreg[p];
      }
      __syncthreads();
    }
  }

  // normalize + write [B][S][HQ*DH]
#pragma unroll
  for (int mf = 0; mf < 2; ++mf) {
    int s = qt * 128 + wid * 32 + mf * 16 + qi;
    float invl = 1.f / lrow[mf];
    size_t base = ((size_t)b * SEQ + s) * 1024 + hq * 64;
#pragma unroll
    for (int nf2 = 0; nf2 < 4; ++nf2) {
      half4 o;
#pragma unroll
      for (int j = 0; j < 4; ++j) o[j] = (_Float16)(oacc[mf][nf2][j] * invl);
      *(half4*)(oh + base + nf2 * 16 + g * 4) = o;
    }
  }
}

// ---------------- K3: output projection, fp32 out ----------------
__global__ __launch_bounds__(256) void gemm_out(
    const _Float16* __restrict__ ah, const _Float16* __restrict__ WoT,
    float* __restrict__ out) {
  __shared__ char As[128 * 64 * 2];
  __shared__ char Bs[128 * 64 * 2];
  int tid = threadIdx.x, lane = tid & 63, wid = tid >> 6;
  int wr = wid >> 1, wc = wid & 1;
  int bm = blockIdx.x, bn = blockIdx.y;
  const _Float16* Ag = ah + (size_t)bm * 128 * KD;
  const _Float16* Bg = WoT + (size_t)bn * 128 * KD;
  f32x4 acc[4][4] = {};

  for (int kt = 0; kt < KD / 64; ++kt) {
#pragma unroll
    for (int p = 0; p < 4; ++p) {
      int idx = tid + p * 256;
      int r = idx >> 3, k8 = idx & 7;
      half8 va = *(const half8*)(Ag + (size_t)r * KD + kt * 64 + k8 * 8);
      *(half8*)(As + r * 128 + SWZ(r, k8 * 16)) = va;
      half8 vb = *(const half8*)(Bg + (size_t)r * KD + kt * 64 + k8 * 8);
      *(half8*)(Bs + r * 128 + SWZ(r, k8 * 16)) = vb;
    }
    __syncthreads();
#pragma unroll
    for (int kk = 0; kk < 2; ++kk) {
      int kb = kk * 64 + (lane >> 4) * 16;
      half8 af[4], bf[4];
#pragma unroll
      for (int mf = 0; mf < 4; ++mf) {
        int r = wr * 64 + mf * 16 + (lane & 15);
        af[mf] = *(const half8*)(As + r * 128 + SWZ(r, kb));
      }
#pragma unroll
      for (int nf = 0; nf < 4; ++nf) {
        int r = wc * 64 + nf * 16 + (lane & 15);
        bf[nf] = *(const half8*)(Bs + r * 128 + SWZ(r, kb));
      }
#pragma unroll
      for (int mf = 0; mf < 4; ++mf)
#pragma unroll
        for (int nf = 0; nf < 4; ++nf)
          acc[mf][nf] = __builtin_amdgcn_mfma_f32_16x16x32_f16(af[mf], bf[nf], acc[mf][nf], 0, 0, 0);
    }
    __syncthreads();
  }

  int row0 = bm * 128 + wr * 64, col0 = bn * 128 + wc * 64;
#pragma unroll
  for (int mf = 0; mf < 4; ++mf)
#pragma unroll
    for (int j = 0; j < 4; ++j) {
      int row = row0 + mf * 16 + (lane >> 4) * 4 + j;
#pragma unroll
      for (int nf = 0; nf < 4; ++nf)
        out[(size_t)row * 1024 + col0 + nf * 16 + (lane & 15)] = acc[mf][nf][j];
    }
}

// ---------------- launch ----------------
extern "C" void kernel_launch(void* const* d_in, const int* in_sizes, int n_in,
                              void* d_out, int out_size, void* d_ws, size_t ws_size,
                              hipStream_t stream) {
  const float* x  = (const float*)d_in[0];
  const int* qpos = (const int*)d_in[1];
  const float* Wq = (const float*)d_in[2];
  const float* Wk = (const float*)d_in[3];
  const float* Wv = (const float*)d_in[4];
  const float* Wo = (const float*)d_in[5];
  float* out = (float*)d_out;

  char* ws = (char*)d_ws;
  _Float16* xh  = (_Float16*)(ws);                 // 8 MB  [4096][1024]
  _Float16* WT  = (_Float16*)(ws + 8388608);       // 3 MB  [1536][1024] (q,k,v stacked)
  _Float16* WoT = (_Float16*)(ws + 11534336);      // 2 MB  [1024][1024]
  _Float16* qhp = (_Float16*)(ws + 13631488);      // 8 MB  [B][HQ][S][D]
  _Float16* khp = (_Float16*)(ws + 22020096);      // 2 MB  [B][HK][S][D]
  _Float16* vhp = (_Float16*)(ws + 24117248);      // 2 MB  [B][HK][S][D]
  _Float16* ohp = (_Float16*)(ws + 26214400);      // 8 MB  [4096][1024]
  float2*   rtab = (float2*)(ws + 34603008);       // 1 MB  [4096][32]
  _Float16* vtp = (_Float16*)(ws + 35651584);      // 2 MB  [B][HK][D][S]

  cvt_x_kernel<<<4096, 256, 0, stream>>>(x, xh, 1048576);
  rope_tab_kernel<<<512, 256, 0, stream>>>(qpos, rtab);
  transpose_w_kernel<<<dim3(16, 16), 256, 0, stream>>>(Wq, WT, 1024, 0);
  transpose_w_kernel<<<dim3(4, 16), 256, 0, stream>>>(Wk, WT, 256, 1024);
  transpose_w_kernel<<<dim3(4, 16), 256, 0, stream>>>(Wv, WT, 256, 1280);
  transpose_w_kernel<<<dim3(16, 16), 256, 0, stream>>>(Wo, WoT, 1024, 0);
  gemm_qkv_rope<<<dim3(32, 12), 256, 0, stream>>>(xh, WT, rtab, qhp, khp, vhp);
  transpose_v_kernel<<<dim3(32, 8), 256, 0, stream>>>(vhp, vtp);
  attn_kernel<<<dim3(16, 32), 256, 0, stream>>>(qhp, khp, vtp, ohp);
  gemm_out<<<dim3(32, 8), 256, 0, stream>>>(ohp, WoT, out);
}

// Round 7
// 131.295 us; speedup vs baseline: 1.1591x; 1.1591x over previous
//
#include <hip/hip_runtime.h>
#include <hip/hip_fp16.h>
#include <math.h>

typedef __attribute__((ext_vector_type(8))) _Float16 half8;
typedef __attribute__((ext_vector_type(4))) _Float16 half4;
typedef __attribute__((ext_vector_type(4))) float f32x4;
typedef __attribute__((ext_vector_type(16))) float f32x16;
typedef __attribute__((ext_vector_type(4))) unsigned uint4v;

#define HQ 16
#define HK 4
#define DH 64
#define NB 2
#define SEQ 2048
#define EDIM 1024
#define KD 1024

// ---------------- prep: convert x to f16 ----------------
__global__ __launch_bounds__(256) void cvt_x_kernel(const float* __restrict__ x,
                                                    _Float16* __restrict__ xh, int n4) {
  int i = blockIdx.x * 256 + threadIdx.x;
  if (i >= n4) return;
  float4 v = ((const float4*)x)[i];
  half4 h;
  h[0] = (_Float16)v.x; h[1] = (_Float16)v.y; h[2] = (_Float16)v.z; h[3] = (_Float16)v.w;
  *(half4*)(xh + (size_t)i * 4) = h;
}

// ---------------- prep: RoPE sin/cos table [4096 rows][32 freqs] ----------------
__global__ __launch_bounds__(256) void rope_tab_kernel(const int* __restrict__ qpos,
                                                       float2* __restrict__ tab) {
  int i = blockIdx.x * 256 + threadIdx.x;   // 0 .. 4096*32-1
  int row = i >> 5, d = i & 31;
  float ang = (float)qpos[row] * expf((float)d * -0.2878231366242558f); // -ln(10000)/32
  float sn, cs;
  sincosf(ang, &sn, &cs);
  tab[i] = make_float2(sn, cs);
}

// ---------------- prep: W [K][N] f32 -> WT [N][K] f16 ----------------
__global__ __launch_bounds__(256) void transpose_w_kernel(const float* __restrict__ W,
                                                          _Float16* __restrict__ WT,
                                                          int N, int row_off) {
  __shared__ float t[64][65];
  int n0 = blockIdx.x * 64, k0 = blockIdx.y * 64;
  int tid = threadIdx.x;
#pragma unroll
  for (int p = 0; p < 4; ++p) {
    int idx = tid + p * 256;
    int r = idx >> 4;      // k row 0..63
    int c4 = idx & 15;     // float4 col
    float4 v = *(const float4*)(W + (size_t)(k0 + r) * N + n0 + c4 * 4);
    t[r][c4 * 4 + 0] = v.x; t[r][c4 * 4 + 1] = v.y;
    t[r][c4 * 4 + 2] = v.z; t[r][c4 * 4 + 3] = v.w;
  }
  __syncthreads();
#pragma unroll
  for (int p = 0; p < 4; ++p) {
    int idx = tid + p * 256;
    int n = idx >> 4;
    int k4 = idx & 15;
    half4 h;
    h[0] = (_Float16)t[k4 * 4 + 0][n]; h[1] = (_Float16)t[k4 * 4 + 1][n];
    h[2] = (_Float16)t[k4 * 4 + 2][n]; h[3] = (_Float16)t[k4 * 4 + 3][n];
    *(half4*)(WT + (size_t)(row_off + n0 + n) * KD + k0 + k4 * 4) = h;
  }
}

// ---------------- prep: V [bh][s][d] -> V^T [bh][d][s] ----------------
__global__ __launch_bounds__(256) void transpose_v_kernel(const _Float16* __restrict__ vhp,
                                                          _Float16* __restrict__ vtp) {
  __shared__ _Float16 t[64][72];
  int bh = blockIdx.y;           // 0..7  (b*HK+hk)
  int s0 = blockIdx.x * 64;      // 32 tiles over SEQ
  const _Float16* src = vhp + ((size_t)bh * SEQ + s0) * DH;
  _Float16* dst = vtp + (size_t)bh * DH * SEQ + s0;
  int tid = threadIdx.x;
#pragma unroll
  for (int p = 0; p < 2; ++p) {
    int idx = tid + p * 256;     // 512 half8s
    int r = idx >> 3, c8 = idx & 7;
    half8 v = *(const half8*)(src + (size_t)r * DH + c8 * 8);
#pragma unroll
    for (int i = 0; i < 8; ++i) t[r][c8 * 8 + i] = v[i];
  }
  __syncthreads();
#pragma unroll
  for (int p = 0; p < 2; ++p) {
    int idx = tid + p * 256;
    int d = idx >> 3, c8 = idx & 7;
    half8 v;
#pragma unroll
    for (int i = 0; i < 8; ++i) v[i] = t[c8 * 8 + i][d];
    *(half8*)(dst + (size_t)d * SEQ + c8 * 8) = v;
  }
}

// swizzle: XOR bits 4-6 of the byte offset with row&7 (row stride 128B tiles)
#define SWZ(r, kb) ((kb) ^ (((r) & 7) << 4))

// ---------------- K1: fused QKV GEMM + RoPE (table-driven) ----------------
// C[4096][1536] = xh[4096][1024] @ W; cols 0-1023 -> q, 1024-1279 -> k, 1280-1535 -> v
__global__ __launch_bounds__(256) void gemm_qkv_rope(
    const _Float16* __restrict__ xh, const _Float16* __restrict__ WT,
    const float2* __restrict__ rtab,
    _Float16* __restrict__ qh, _Float16* __restrict__ kh, _Float16* __restrict__ vh) {
  __shared__ char As[128 * 64 * 2];
  __shared__ char Bs[128 * 64 * 2];
  int tid = threadIdx.x, lane = tid & 63, wid = tid >> 6;
  int wr = wid >> 1, wc = wid & 1;
  int bm = blockIdx.x, bn = blockIdx.y;

  const _Float16* Ag = xh + (size_t)bm * 128 * KD;
  const _Float16* Bg = WT + (size_t)bn * 128 * KD;

  f32x4 acc[4][4] = {};

  for (int kt = 0; kt < KD / 64; ++kt) {
#pragma unroll
    for (int p = 0; p < 4; ++p) {
      int idx = tid + p * 256;
      int r = idx >> 3, k8 = idx & 7;
      half8 va = *(const half8*)(Ag + (size_t)r * KD + kt * 64 + k8 * 8);
      *(half8*)(As + r * 128 + SWZ(r, k8 * 16)) = va;
      half8 vb = *(const half8*)(Bg + (size_t)r * KD + kt * 64 + k8 * 8);
      *(half8*)(Bs + r * 128 + SWZ(r, k8 * 16)) = vb;
    }
    __syncthreads();
#pragma unroll
    for (int kk = 0; kk < 2; ++kk) {
      int kb = kk * 64 + (lane >> 4) * 16;
      half8 af[4], bf[4];
#pragma unroll
      for (int mf = 0; mf < 4; ++mf) {
        int r = wr * 64 + mf * 16 + (lane & 15);
        af[mf] = *(const half8*)(As + r * 128 + SWZ(r, kb));
      }
#pragma unroll
      for (int nf = 0; nf < 4; ++nf) {
        int r = wc * 64 + nf * 16 + (lane & 15);
        bf[nf] = *(const half8*)(Bs + r * 128 + SWZ(r, kb));
      }
#pragma unroll
      for (int mf = 0; mf < 4; ++mf)
#pragma unroll
        for (int nf = 0; nf < 4; ++nf)
          acc[mf][nf] = __builtin_amdgcn_mfma_f32_16x16x32_f16(af[mf], bf[nf], acc[mf][nf], 0, 0, 0);
    }
    __syncthreads();
  }

  // epilogue: wave covers 64 contiguous cols = exactly one head
  int col0 = bn * 128 + wc * 64;
  int row_base = bm * 128 + wr * 64;
#pragma unroll
  for (int mf = 0; mf < 4; ++mf) {
#pragma unroll
    for (int j = 0; j < 4; ++j) {
      int row = row_base + mf * 16 + (lane >> 4) * 4 + j;
      int b = row >> 11, s = row & (SEQ - 1);
      if (col0 < 1024) {
        int hq = col0 >> 6;
        size_t base = (((size_t)b * HQ + hq) * SEQ + s) * DH;
#pragma unroll
        for (int nf = 0; nf < 2; ++nf) {
          int d = nf * 16 + (lane & 15);  // 0..31
          float2 scv = rtab[row * 32 + d];
          float x1 = acc[mf][nf][j], x2 = acc[mf][nf + 2][j];
          qh[base + d]      = (_Float16)(x1 * scv.y - x2 * scv.x);
          qh[base + d + 32] = (_Float16)(x2 * scv.y + x1 * scv.x);
        }
      } else if (col0 < 1280) {
        int hk = (col0 - 1024) >> 6;
        size_t base = (((size_t)b * HK + hk) * SEQ + s) * DH;
#pragma unroll
        for (int nf = 0; nf < 2; ++nf) {
          int d = nf * 16 + (lane & 15);
          float2 scv = rtab[row * 32 + d];
          float x1 = acc[mf][nf][j], x2 = acc[mf][nf + 2][j];
          kh[base + d]      = (_Float16)(x1 * scv.y - x2 * scv.x);
          kh[base + d + 32] = (_Float16)(x2 * scv.y + x1 * scv.x);
        }
      } else {
        int hk = (col0 - 1280) >> 6;
        size_t base = (((size_t)b * HK + hk) * SEQ + s) * DH;
#pragma unroll
        for (int nf = 0; nf < 4; ++nf) {
          int d = nf * 16 + (lane & 15);
          vh[base + d] = (_Float16)acc[mf][nf][j];
        }
      }
    }
  }
}

// ---------------- K2: flash attention, 32x32 MFMA, in-register P ----------------
// grid: (qt=16, bh=32). block 256 = 4 waves x 32 q-rows. KV tile = 128.
// V pre-transposed: vt[bh][d][s]. Q pre-scaled by log2e; exp -> exp2.
// Swapped QK^T (S^T = K Q^T) with 32x32x16: lane holds S[q=lane&31][64 kv vals].
// PV B-frag built in-register: cvt_pkrtz + shfl_xor(32) + cndmask (no P LDS).
__global__ __launch_bounds__(256) void attn_kernel(
    const _Float16* __restrict__ qh, const _Float16* __restrict__ kh,
    const _Float16* __restrict__ vt, _Float16* __restrict__ oh) {
  __shared__ char Ks[128 * 64 * 2];      // 16KB [kv][d] swz, row 128B
  __shared__ char Vs[64 * 128 * 2];      // 16KB [d][kv] swz, row 256B

  int tid = threadIdx.x, lane = tid & 63, wid = tid >> 6;
  int half = lane >> 5, l31 = lane & 31;
  bool lopart = (half == 0);
  int qt = blockIdx.x, bh = blockIdx.y;
  int b = bh >> 4, hq = bh & 15, hk = hq >> 2;

  const _Float16* Qg = qh + (((size_t)b * HQ + hq) * SEQ + qt * 128 + wid * 32 + l31) * DH;
  const _Float16* Kg = kh + (((size_t)b * HK + hk) * SEQ) * DH;
  const _Float16* Vtg = vt + (size_t)(b * HK + hk) * DH * SEQ;

  int kr = tid >> 3, kd8 = tid & 7;      // K stage: rows kr+32p
  int vr = tid >> 4, vc8 = tid & 15;     // V stage: rows vr+16p

  // Q as B-fragments: lane holds Q[q=l31][d = ks*16 + half*8 + i], pre-scaled
  const _Float16 l2e = (_Float16)1.44269504f;
  half8 qf[4];
#pragma unroll
  for (int ks = 0; ks < 4; ++ks) {
    half8 q0 = *(const half8*)(Qg + ks * 16 + half * 8);
#pragma unroll
    for (int i = 0; i < 8; ++i) q0[i] = q0[i] * l2e;
    qf[ks] = q0;
  }

  f32x16 oacc[2] = {};   // O^T: [dblk]; lane: q=l31, d=dblk*32+(r&3)+8*(r>>2)+4*half
  float m = -3e38f, l = 0.f;

  for (int kt = 0; kt < SEQ / 128; ++kt) {
    // stage K [128 kv][64 d] and V^T [64 d][128 kv], vectorized + swz
#pragma unroll
    for (int p = 0; p < 4; ++p) {
      int r = kr + p * 32;
      *(half8*)(Ks + r * 128 + SWZ(r, kd8 * 16)) =
          *(const half8*)(Kg + (size_t)(kt * 128 + r) * DH + kd8 * 8);
      int d = vr + p * 16;
      *(half8*)(Vs + d * 256 + SWZ(d, vc8 * 16)) =
          *(const half8*)(Vtg + (size_t)d * SEQ + kt * 128 + vc8 * 8);
    }
    __syncthreads();

    // S^T = K Q^T : 4 kv-blocks of 32, K-dim d=64 in 4 slices of 16
    f32x16 sacc[4] = {};
    __builtin_amdgcn_s_setprio(1);
#pragma unroll
    for (int b4 = 0; b4 < 4; ++b4) {
      int r = b4 * 32 + l31;
#pragma unroll
      for (int ks = 0; ks < 4; ++ks) {
        half8 kf = *(const half8*)(Ks + r * 128 + SWZ(r, ks * 32 + half * 16));
        sacc[b4] = __builtin_amdgcn_mfma_f32_32x32x16_f16(kf, qf[ks], sacc[b4], 0, 0, 0);
      }
    }
    __builtin_amdgcn_s_setprio(0);

    // row max: lane's 64 values + partner (lane^32)
    float pm = sacc[0][0];
#pragma unroll
    for (int b4 = 0; b4 < 4; ++b4)
#pragma unroll
      for (int r = 0; r < 16; ++r)
        if (b4 || r) pm = fmaxf(pm, sacc[b4][r]);
    pm = fmaxf(pm, __shfl_xor(pm, 32, 64));
    float mnew = fmaxf(m, pm);
    float alpha = __builtin_amdgcn_exp2f(m - mnew);
    m = mnew;
    oacc[0] *= alpha;
    oacc[1] *= alpha;
    l *= alpha;
    float ps = 0.f;

    // per kv-block: exp, pack, build PV B-frags in-register, PV MFMA
#pragma unroll
    for (int b4 = 0; b4 < 4; ++b4) {
      float e[16];
#pragma unroll
      for (int r = 0; r < 16; ++r) {
        e[r] = __builtin_amdgcn_exp2f(sacc[b4][r] - m);
        ps += e[r];
      }
      unsigned W0[4], W1[4];
#pragma unroll
      for (int qd = 0; qd < 4; ++qd) {
        W0[qd] = __builtin_bit_cast(unsigned, __builtin_amdgcn_cvt_pkrtz(e[4 * qd + 0], e[4 * qd + 1]));
        W1[qd] = __builtin_bit_cast(unsigned, __builtin_amdgcn_cvt_pkrtz(e[4 * qd + 2], e[4 * qd + 3]));
      }
      half8 pf[2];
#pragma unroll
      for (int s = 0; s < 2; ++s) {
        // exchange across lane^32: one shfl moves both directions' needed word
        unsigned selA = lopart ? W0[2 * s + 1] : W0[2 * s];
        unsigned crA = (unsigned)__shfl_xor((int)selA, 32, 64);
        unsigned selB = lopart ? W1[2 * s + 1] : W1[2 * s];
        unsigned crB = (unsigned)__shfl_xor((int)selB, 32, 64);
        uint4v u;
        u[0] = lopart ? W0[2 * s] : crA;       // kv +0,1
        u[1] = lopart ? W1[2 * s] : crB;       // kv +2,3
        u[2] = lopart ? crA : W0[2 * s + 1];   // kv +4,5
        u[3] = lopart ? crB : W1[2 * s + 1];   // kv +6,7
        pf[s] = __builtin_bit_cast(half8, u);
      }
      __builtin_amdgcn_s_setprio(1);
#pragma unroll
      for (int s = 0; s < 2; ++s) {
        int kvb = b4 * 64 + s * 32 + half * 16;
#pragma unroll
        for (int dblk = 0; dblk < 2; ++dblk) {
          int d = dblk * 32 + l31;
          half8 vf = *(const half8*)(Vs + d * 256 + SWZ(d, kvb));
          oacc[dblk] = __builtin_amdgcn_mfma_f32_32x32x16_f16(vf, pf[s], oacc[dblk], 0, 0, 0);
        }
      }
      __builtin_amdgcn_s_setprio(0);
    }
    ps += __shfl_xor(ps, 32, 64);
    l += ps;
    __syncthreads();
  }

  // normalize + write [B][S][HQ*DH]; lane owns q = l31, 32 d-values per dblk
  int s = qt * 128 + wid * 32 + l31;
  float invl = 1.f / l;
  size_t base = ((size_t)b * SEQ + s) * 1024 + hq * 64;
#pragma unroll
  for (int dblk = 0; dblk < 2; ++dblk) {
#pragma unroll
    for (int qd = 0; qd < 4; ++qd) {
      half4 o;
#pragma unroll
      for (int j = 0; j < 4; ++j) o[j] = (_Float16)(oacc[dblk][qd * 4 + j] * invl);
      *(half4*)(oh + base + dblk * 32 + qd * 8 + half * 4) = o;
    }
  }
}

// ---------------- K3: output projection, fp32 out ----------------
__global__ __launch_bounds__(256) void gemm_out(
    const _Float16* __restrict__ ah, const _Float16* __restrict__ WoT,
    float* __restrict__ out) {
  __shared__ char As[128 * 64 * 2];
  __shared__ char Bs[128 * 64 * 2];
  int tid = threadIdx.x, lane = tid & 63, wid = tid >> 6;
  int wr = wid >> 1, wc = wid & 1;
  int bm = blockIdx.x, bn = blockIdx.y;
  const _Float16* Ag = ah + (size_t)bm * 128 * KD;
  const _Float16* Bg = WoT + (size_t)bn * 128 * KD;
  f32x4 acc[4][4] = {};

  for (int kt = 0; kt < KD / 64; ++kt) {
#pragma unroll
    for (int p = 0; p < 4; ++p) {
      int idx = tid + p * 256;
      int r = idx >> 3, k8 = idx & 7;
      half8 va = *(const half8*)(Ag + (size_t)r * KD + kt * 64 + k8 * 8);
      *(half8*)(As + r * 128 + SWZ(r, k8 * 16)) = va;
      half8 vb = *(const half8*)(Bg + (size_t)r * KD + kt * 64 + k8 * 8);
      *(half8*)(Bs + r * 128 + SWZ(r, k8 * 16)) = vb;
    }
    __syncthreads();
#pragma unroll
    for (int kk = 0; kk < 2; ++kk) {
      int kb = kk * 64 + (lane >> 4) * 16;
      half8 af[4], bf[4];
#pragma unroll
      for (int mf = 0; mf < 4; ++mf) {
        int r = wr * 64 + mf * 16 + (lane & 15);
        af[mf] = *(const half8*)(As + r * 128 + SWZ(r, kb));
      }
#pragma unroll
      for (int nf = 0; nf < 4; ++nf) {
        int r = wc * 64 + nf * 16 + (lane & 15);
        bf[nf] = *(const half8*)(Bs + r * 128 + SWZ(r, kb));
      }
#pragma unroll
      for (int mf = 0; mf < 4; ++mf)
#pragma unroll
        for (int nf = 0; nf < 4; ++nf)
          acc[mf][nf] = __builtin_amdgcn_mfma_f32_16x16x32_f16(af[mf], bf[nf], acc[mf][nf], 0, 0, 0);
    }
    __syncthreads();
  }

  int row0 = bm * 128 + wr * 64, col0 = bn * 128 + wc * 64;
#pragma unroll
  for (int mf = 0; mf < 4; ++mf)
#pragma unroll
    for (int j = 0; j < 4; ++j) {
      int row = row0 + mf * 16 + (lane >> 4) * 4 + j;
#pragma unroll
      for (int nf = 0; nf < 4; ++nf)
        out[(size_t)row * 1024 + col0 + nf * 16 + (lane & 15)] = acc[mf][nf][j];
    }
}

// ---------------- launch ----------------
extern "C" void kernel_launch(void* const* d_in, const int* in_sizes, int n_in,
                              void* d_out, int out_size, void* d_ws, size_t ws_size,
                              hipStream_t stream) {
  const float* x  = (const float*)d_in[0];
  const int* qpos = (const int*)d_in[1];
  const float* Wq = (const float*)d_in[2];
  const float* Wk = (const float*)d_in[3];
  const float* Wv = (const float*)d_in[4];
  const float* Wo = (const float*)d_in[5];
  float* out = (float*)d_out;

  char* ws = (char*)d_ws;
  _Float16* xh  = (_Float16*)(ws);                 // 8 MB  [4096][1024]
  _Float16* WT  = (_Float16*)(ws + 8388608);       // 3 MB  [1536][1024] (q,k,v stacked)
  _Float16* WoT = (_Float16*)(ws + 11534336);      // 2 MB  [1024][1024]
  _Float16* qhp = (_Float16*)(ws + 13631488);      // 8 MB  [B][HQ][S][D]
  _Float16* khp = (_Float16*)(ws + 22020096);      // 2 MB  [B][HK][S][D]
  _Float16* vhp = (_Float16*)(ws + 24117248);      // 2 MB  [B][HK][S][D]
  _Float16* ohp = (_Float16*)(ws + 26214400);      // 8 MB  [4096][1024]
  float2*   rtab = (float2*)(ws + 34603008);       // 1 MB  [4096][32]
  _Float16* vtp = (_Float16*)(ws + 35651584);      // 2 MB  [B][HK][D][S]

  cvt_x_kernel<<<4096, 256, 0, stream>>>(x, xh, 1048576);
  rope_tab_kernel<<<512, 256, 0, stream>>>(qpos, rtab);
  transpose_w_kernel<<<dim3(16, 16), 256, 0, stream>>>(Wq, WT, 1024, 0);
  transpose_w_kernel<<<dim3(4, 16), 256, 0, stream>>>(Wk, WT, 256, 1024);
  transpose_w_kernel<<<dim3(4, 16), 256, 0, stream>>>(Wv, WT, 256, 1280);
  transpose_w_kernel<<<dim3(16, 16), 256, 0, stream>>>(Wo, WoT, 1024, 0);
  gemm_qkv_rope<<<dim3(32, 12), 256, 0, stream>>>(xh, WT, rtab, qhp, khp, vhp);
  transpose_v_kernel<<<dim3(32, 8), 256, 0, stream>>>(vhp, vtp);
  attn_kernel<<<dim3(16, 32), 256, 0, stream>>>(qhp, khp, vtp, ohp);
  gemm_out<<<dim3(32, 8), 256, 0, stream>>>(ohp, WoT, out);
}

// Round 8
// 128.658 us; speedup vs baseline: 1.1829x; 1.0205x over previous
//
#include <hip/hip_runtime.h>
#include <hip/hip_fp16.h>
#include <math.h>

typedef __attribute__((ext_vector_type(8))) _Float16 half8;
typedef __attribute__((ext_vector_type(4))) _Float16 half4;
typedef __attribute__((ext_vector_type(4))) float f32x4;
typedef __attribute__((ext_vector_type(16))) float f32x16;
typedef __attribute__((ext_vector_type(4))) unsigned uint4v;

#define HQ 16
#define HK 4
#define DH 64
#define NB 2
#define SEQ 2048
#define EDIM 1024
#define KD 1024

// direct global->LDS 16B async copy; LDS dest = wave-uniform base + lane*16
__device__ __forceinline__ void gload16(const void* g, void* l) {
  __builtin_amdgcn_global_load_lds(
      (const __attribute__((address_space(1))) void*)g,
      (__attribute__((address_space(3))) void*)l, 16, 0, 0);
}

// ---------------- prep: convert x to f16 ----------------
__global__ __launch_bounds__(256) void cvt_x_kernel(const float* __restrict__ x,
                                                    _Float16* __restrict__ xh, int n4) {
  int i = blockIdx.x * 256 + threadIdx.x;
  if (i >= n4) return;
  float4 v = ((const float4*)x)[i];
  half4 h;
  h[0] = (_Float16)v.x; h[1] = (_Float16)v.y; h[2] = (_Float16)v.z; h[3] = (_Float16)v.w;
  *(half4*)(xh + (size_t)i * 4) = h;
}

// ---------------- prep: RoPE sin/cos table [4096 rows][32 freqs] ----------------
__global__ __launch_bounds__(256) void rope_tab_kernel(const int* __restrict__ qpos,
                                                       float2* __restrict__ tab) {
  int i = blockIdx.x * 256 + threadIdx.x;   // 0 .. 4096*32-1
  int row = i >> 5, d = i & 31;
  float ang = (float)qpos[row] * expf((float)d * -0.2878231366242558f); // -ln(10000)/32
  float sn, cs;
  sincosf(ang, &sn, &cs);
  tab[i] = make_float2(sn, cs);
}

// ---------------- prep: W [K][N] f32 -> WT [N][K] f16 ----------------
__global__ __launch_bounds__(256) void transpose_w_kernel(const float* __restrict__ W,
                                                          _Float16* __restrict__ WT,
                                                          int N, int row_off) {
  __shared__ float t[64][65];
  int n0 = blockIdx.x * 64, k0 = blockIdx.y * 64;
  int tid = threadIdx.x;
#pragma unroll
  for (int p = 0; p < 4; ++p) {
    int idx = tid + p * 256;
    int r = idx >> 4;      // k row 0..63
    int c4 = idx & 15;     // float4 col
    float4 v = *(const float4*)(W + (size_t)(k0 + r) * N + n0 + c4 * 4);
    t[r][c4 * 4 + 0] = v.x; t[r][c4 * 4 + 1] = v.y;
    t[r][c4 * 4 + 2] = v.z; t[r][c4 * 4 + 3] = v.w;
  }
  __syncthreads();
#pragma unroll
  for (int p = 0; p < 4; ++p) {
    int idx = tid + p * 256;
    int n = idx >> 4;
    int k4 = idx & 15;
    half4 h;
    h[0] = (_Float16)t[k4 * 4 + 0][n]; h[1] = (_Float16)t[k4 * 4 + 1][n];
    h[2] = (_Float16)t[k4 * 4 + 2][n]; h[3] = (_Float16)t[k4 * 4 + 3][n];
    *(half4*)(WT + (size_t)(row_off + n0 + n) * KD + k0 + k4 * 4) = h;
  }
}

// ---------------- prep: V [bh][s][d] -> V^T [bh][d][s] ----------------
__global__ __launch_bounds__(256) void transpose_v_kernel(const _Float16* __restrict__ vhp,
                                                          _Float16* __restrict__ vtp) {
  __shared__ _Float16 t[64][72];
  int bh = blockIdx.y;           // 0..7  (b*HK+hk)
  int s0 = blockIdx.x * 64;      // 32 tiles over SEQ
  const _Float16* src = vhp + ((size_t)bh * SEQ + s0) * DH;
  _Float16* dst = vtp + (size_t)bh * DH * SEQ + s0;
  int tid = threadIdx.x;
#pragma unroll
  for (int p = 0; p < 2; ++p) {
    int idx = tid + p * 256;     // 512 half8s
    int r = idx >> 3, c8 = idx & 7;
    half8 v = *(const half8*)(src + (size_t)r * DH + c8 * 8);
#pragma unroll
    for (int i = 0; i < 8; ++i) t[r][c8 * 8 + i] = v[i];
  }
  __syncthreads();
#pragma unroll
  for (int p = 0; p < 2; ++p) {
    int idx = tid + p * 256;
    int d = idx >> 3, c8 = idx & 7;
    half8 v;
#pragma unroll
    for (int i = 0; i < 8; ++i) v[i] = t[c8 * 8 + i][d];
    *(half8*)(dst + (size_t)d * SEQ + c8 * 8) = v;
  }
}

// swizzle: XOR bits 4-6 of the byte offset with row&7 (row stride 128B tiles)
#define SWZ(r, kb) ((kb) ^ (((r) & 7) << 4))

// ---------------- K1: fused QKV GEMM + RoPE (table-driven) ----------------
// C[4096][1536] = xh[4096][1024] @ W; cols 0-1023 -> q, 1024-1279 -> k, 1280-1535 -> v
// staging via global_load_lds, pre-swizzled global source (LDS dest linear)
__global__ __launch_bounds__(256) void gemm_qkv_rope(
    const _Float16* __restrict__ xh, const _Float16* __restrict__ WT,
    const float2* __restrict__ rtab,
    _Float16* __restrict__ qh, _Float16* __restrict__ kh, _Float16* __restrict__ vh) {
  __shared__ char As[128 * 64 * 2];
  __shared__ char Bs[128 * 64 * 2];
  int tid = threadIdx.x, lane = tid & 63, wid = tid >> 6;
  int wr = wid >> 1, wc = wid & 1;
  int bm = blockIdx.x, bn = blockIdx.y;

  const char* Ag = (const char*)(xh + (size_t)bm * 128 * KD);
  const char* Bg = (const char*)(WT + (size_t)bn * 128 * KD);

  int colS = 16 * ((lane & 7) ^ (lane >> 3));      // pre-swizzled source col (bytes)
  int rS = (lane >> 3);

  f32x4 acc[4][4] = {};

  for (int kt = 0; kt < KD / 64; ++kt) {
#pragma unroll
    for (int p = 0; p < 4; ++p) {
      int r = (wid * 4 + p) * 8 + rS;
      gload16(Ag + (size_t)r * (KD * 2) + kt * 128 + colS, As + (wid * 4 + p) * 1024);
      gload16(Bg + (size_t)r * (KD * 2) + kt * 128 + colS, Bs + (wid * 4 + p) * 1024);
    }
    __syncthreads();
#pragma unroll
    for (int kk = 0; kk < 2; ++kk) {
      int kb = kk * 64 + (lane >> 4) * 16;
      half8 af[4], bf[4];
#pragma unroll
      for (int mf = 0; mf < 4; ++mf) {
        int r = wr * 64 + mf * 16 + (lane & 15);
        af[mf] = *(const half8*)(As + r * 128 + SWZ(r, kb));
      }
#pragma unroll
      for (int nf = 0; nf < 4; ++nf) {
        int r = wc * 64 + nf * 16 + (lane & 15);
        bf[nf] = *(const half8*)(Bs + r * 128 + SWZ(r, kb));
      }
#pragma unroll
      for (int mf = 0; mf < 4; ++mf)
#pragma unroll
        for (int nf = 0; nf < 4; ++nf)
          acc[mf][nf] = __builtin_amdgcn_mfma_f32_16x16x32_f16(af[mf], bf[nf], acc[mf][nf], 0, 0, 0);
    }
    __syncthreads();
  }

  // epilogue: wave covers 64 contiguous cols = exactly one head
  int col0 = bn * 128 + wc * 64;
  int row_base = bm * 128 + wr * 64;
#pragma unroll
  for (int mf = 0; mf < 4; ++mf) {
#pragma unroll
    for (int j = 0; j < 4; ++j) {
      int row = row_base + mf * 16 + (lane >> 4) * 4 + j;
      int b = row >> 11, s = row & (SEQ - 1);
      if (col0 < 1024) {
        int hq = col0 >> 6;
        size_t base = (((size_t)b * HQ + hq) * SEQ + s) * DH;
#pragma unroll
        for (int nf = 0; nf < 2; ++nf) {
          int d = nf * 16 + (lane & 15);  // 0..31
          float2 scv = rtab[row * 32 + d];
          float x1 = acc[mf][nf][j], x2 = acc[mf][nf + 2][j];
          qh[base + d]      = (_Float16)(x1 * scv.y - x2 * scv.x);
          qh[base + d + 32] = (_Float16)(x2 * scv.y + x1 * scv.x);
        }
      } else if (col0 < 1280) {
        int hk = (col0 - 1024) >> 6;
        size_t base = (((size_t)b * HK + hk) * SEQ + s) * DH;
#pragma unroll
        for (int nf = 0; nf < 2; ++nf) {
          int d = nf * 16 + (lane & 15);
          float2 scv = rtab[row * 32 + d];
          float x1 = acc[mf][nf][j], x2 = acc[mf][nf + 2][j];
          kh[base + d]      = (_Float16)(x1 * scv.y - x2 * scv.x);
          kh[base + d + 32] = (_Float16)(x2 * scv.y + x1 * scv.x);
        }
      } else {
        int hk = (col0 - 1280) >> 6;
        size_t base = (((size_t)b * HK + hk) * SEQ + s) * DH;
#pragma unroll
        for (int nf = 0; nf < 4; ++nf) {
          int d = nf * 16 + (lane & 15);
          vh[base + d] = (_Float16)acc[mf][nf][j];
        }
      }
    }
  }
}

// ---------------- K2: flash attention, 32x32 MFMA, in-register P, async dbuf ----------------
// grid: (qt=16, bh=32). block 256 = 4 waves x 32 q-rows. KV tile = 128.
// Double-buffered LDS, global_load_lds with pre-swizzled source, counted vmcnt(8).
__global__ __launch_bounds__(256) void attn_kernel(
    const _Float16* __restrict__ qh, const _Float16* __restrict__ kh,
    const _Float16* __restrict__ vt, _Float16* __restrict__ oh) {
  __shared__ char Ks[2][128 * 64 * 2];   // 2x16KB [kv][d] swz, row 128B
  __shared__ char Vs[2][64 * 128 * 2];   // 2x16KB [d][kv] swz, row 256B

  int tid = threadIdx.x, lane = tid & 63, wid = tid >> 6;
  int half = lane >> 5, l31 = lane & 31;
  bool lopart = (half == 0);
  int qt = blockIdx.x, bh = blockIdx.y;
  int b = bh >> 4, hq = bh & 15, hk = hq >> 2;

  const _Float16* Qg = qh + (((size_t)b * HQ + hq) * SEQ + qt * 128 + wid * 32 + l31) * DH;
  const char* Kg = (const char*)(kh + (((size_t)b * HK + hk) * SEQ) * DH);
  const char* Vtg = (const char*)(vt + (size_t)(b * HK + hk) * DH * SEQ);

  // Q as B-fragments: lane holds Q[q=l31][d = ks*16 + half*8 + i], pre-scaled
  const _Float16 l2e = (_Float16)1.44269504f;
  half8 qf[4];
#pragma unroll
  for (int ks = 0; ks < 4; ++ks) {
    half8 q0 = *(const half8*)(Qg + ks * 16 + half * 8);
#pragma unroll
    for (int i = 0; i < 8; ++i) q0[i] = q0[i] * l2e;
    qf[ks] = q0;
  }

  // staging source addressing (pre-swizzled so linear LDS dest = swizzled layout)
  int colK = 16 * ((lane & 7) ^ (lane >> 3));      // K: fixed per lane
  int rK = lane >> 3;

  f32x16 oacc[2] = {};   // O^T: lane q=l31, d=dblk*32+(r&3)+8*(r>>2)+4*half
  float m = -3e38f, l = 0.f;

  // prologue: stage tile 0 into buf 0
#pragma unroll
  for (int p = 0; p < 4; ++p) {
    int r = (wid * 4 + p) * 8 + rK;
    gload16(Kg + (size_t)r * 128 + colK, Ks[0] + (wid * 4 + p) * 1024);
    int d = (wid * 4 + p) * 4 + (lane >> 4);
    int colV = ((lane & 15) * 16) ^ ((d & 7) << 4);
    gload16(Vtg + (size_t)d * (SEQ * 2) + colV, Vs[0] + (wid * 4 + p) * 1024);
  }

  int cur = 0;
  for (int kt = 0; kt < SEQ / 128; ++kt) {
    if (kt + 1 < SEQ / 128) {
      // issue next tile into the other buffer; stays in flight across compute
#pragma unroll
      for (int p = 0; p < 4; ++p) {
        int r = (wid * 4 + p) * 8 + rK;
        gload16(Kg + (size_t)((kt + 1) * 128 + r) * 128 + colK,
                Ks[cur ^ 1] + (wid * 4 + p) * 1024);
        int d = (wid * 4 + p) * 4 + (lane >> 4);
        int colV = ((lane & 15) * 16) ^ ((d & 7) << 4);
        gload16(Vtg + (size_t)d * (SEQ * 2) + (kt + 1) * 256 + colV,
                Vs[cur ^ 1] + (wid * 4 + p) * 1024);
      }
      asm volatile("s_waitcnt vmcnt(8)" ::: "memory");   // current tile's 8 done
    } else {
      asm volatile("s_waitcnt vmcnt(0)" ::: "memory");
    }
    __builtin_amdgcn_s_barrier();                        // all waves' cur loads done
    const char* KsB = Ks[cur];
    const char* VsB = Vs[cur];

    // S^T = K Q^T : 4 kv-blocks of 32, K-dim d=64 in 4 slices of 16
    f32x16 sacc[4] = {};
    __builtin_amdgcn_s_setprio(1);
#pragma unroll
    for (int b4 = 0; b4 < 4; ++b4) {
      int r = b4 * 32 + l31;
#pragma unroll
      for (int ks = 0; ks < 4; ++ks) {
        half8 kf = *(const half8*)(KsB + r * 128 + SWZ(r, ks * 32 + half * 16));
        sacc[b4] = __builtin_amdgcn_mfma_f32_32x32x16_f16(kf, qf[ks], sacc[b4], 0, 0, 0);
      }
    }
    __builtin_amdgcn_s_setprio(0);

    // row max: lane's 64 values + partner (lane^32)
    float pm = sacc[0][0];
#pragma unroll
    for (int b4 = 0; b4 < 4; ++b4)
#pragma unroll
      for (int r = 0; r < 16; ++r)
        if (b4 || r) pm = fmaxf(pm, sacc[b4][r]);
    pm = fmaxf(pm, __shfl_xor(pm, 32, 64));
    float mnew = fmaxf(m, pm);
    float alpha = __builtin_amdgcn_exp2f(m - mnew);
    m = mnew;
    oacc[0] *= alpha;
    oacc[1] *= alpha;
    l *= alpha;
    float ps = 0.f;

    // per kv-block: exp, pack, build PV B-frags in-register, PV MFMA
#pragma unroll
    for (int b4 = 0; b4 < 4; ++b4) {
      float e[16];
#pragma unroll
      for (int r = 0; r < 16; ++r) {
        e[r] = __builtin_amdgcn_exp2f(sacc[b4][r] - m);
        ps += e[r];
      }
      unsigned W0[4], W1[4];
#pragma unroll
      for (int qd = 0; qd < 4; ++qd) {
        W0[qd] = __builtin_bit_cast(unsigned, __builtin_amdgcn_cvt_pkrtz(e[4 * qd + 0], e[4 * qd + 1]));
        W1[qd] = __builtin_bit_cast(unsigned, __builtin_amdgcn_cvt_pkrtz(e[4 * qd + 2], e[4 * qd + 3]));
      }
      half8 pf[2];
#pragma unroll
      for (int s = 0; s < 2; ++s) {
        unsigned selA = lopart ? W0[2 * s + 1] : W0[2 * s];
        unsigned crA = (unsigned)__shfl_xor((int)selA, 32, 64);
        unsigned selB = lopart ? W1[2 * s + 1] : W1[2 * s];
        unsigned crB = (unsigned)__shfl_xor((int)selB, 32, 64);
        uint4v u;
        u[0] = lopart ? W0[2 * s] : crA;
        u[1] = lopart ? W1[2 * s] : crB;
        u[2] = lopart ? crA : W0[2 * s + 1];
        u[3] = lopart ? crB : W1[2 * s + 1];
        pf[s] = __builtin_bit_cast(half8, u);
      }
      __builtin_amdgcn_s_setprio(1);
#pragma unroll
      for (int s = 0; s < 2; ++s) {
        int kvb = b4 * 64 + s * 32 + half * 16;
#pragma unroll
        for (int dblk = 0; dblk < 2; ++dblk) {
          int d = dblk * 32 + l31;
          half8 vf = *(const half8*)(VsB + d * 256 + SWZ(d, kvb));
          oacc[dblk] = __builtin_amdgcn_mfma_f32_32x32x16_f16(vf, pf[s], oacc[dblk], 0, 0, 0);
        }
      }
      __builtin_amdgcn_s_setprio(0);
    }
    ps += __shfl_xor(ps, 32, 64);
    l += ps;
    __builtin_amdgcn_s_barrier();    // all waves done reading cur before overwrite
    cur ^= 1;
  }

  // normalize + write [B][S][HQ*DH]; lane owns q = l31, 32 d-values per dblk
  int s = qt * 128 + wid * 32 + l31;
  float invl = 1.f / l;
  size_t base = ((size_t)b * SEQ + s) * 1024 + hq * 64;
#pragma unroll
  for (int dblk = 0; dblk < 2; ++dblk) {
#pragma unroll
    for (int qd = 0; qd < 4; ++qd) {
      half4 o;
#pragma unroll
      for (int j = 0; j < 4; ++j) o[j] = (_Float16)(oacc[dblk][qd * 4 + j] * invl);
      *(half4*)(oh + base + dblk * 32 + qd * 8 + half * 4) = o;
    }
  }
}

// ---------------- K3: output projection, fp32 out ----------------
__global__ __launch_bounds__(256) void gemm_out(
    const _Float16* __restrict__ ah, const _Float16* __restrict__ WoT,
    float* __restrict__ out) {
  __shared__ char As[128 * 64 * 2];
  __shared__ char Bs[128 * 64 * 2];
  int tid = threadIdx.x, lane = tid & 63, wid = tid >> 6;
  int wr = wid >> 1, wc = wid & 1;
  int bm = blockIdx.x, bn = blockIdx.y;
  const char* Ag = (const char*)(ah + (size_t)bm * 128 * KD);
  const char* Bg = (const char*)(WoT + (size_t)bn * 128 * KD);
  int colS = 16 * ((lane & 7) ^ (lane >> 3));
  int rS = (lane >> 3);
  f32x4 acc[4][4] = {};

  for (int kt = 0; kt < KD / 64; ++kt) {
#pragma unroll
    for (int p = 0; p < 4; ++p) {
      int r = (wid * 4 + p) * 8 + rS;
      gload16(Ag + (size_t)r * (KD * 2) + kt * 128 + colS, As + (wid * 4 + p) * 1024);
      gload16(Bg + (size_t)r * (KD * 2) + kt * 128 + colS, Bs + (wid * 4 + p) * 1024);
    }
    __syncthreads();
#pragma unroll
    for (int kk = 0; kk < 2; ++kk) {
      int kb = kk * 64 + (lane >> 4) * 16;
      half8 af[4], bf[4];
#pragma unroll
      for (int mf = 0; mf < 4; ++mf) {
        int r = wr * 64 + mf * 16 + (lane & 15);
        af[mf] = *(const half8*)(As + r * 128 + SWZ(r, kb));
      }
#pragma unroll
      for (int nf = 0; nf < 4; ++nf) {
        int r = wc * 64 + nf * 16 + (lane & 15);
        bf[nf] = *(const half8*)(Bs + r * 128 + SWZ(r, kb));
      }
#pragma unroll
      for (int mf = 0; mf < 4; ++mf)
#pragma unroll
        for (int nf = 0; nf < 4; ++nf)
          acc[mf][nf] = __builtin_amdgcn_mfma_f32_16x16x32_f16(af[mf], bf[nf], acc[mf][nf], 0, 0, 0);
    }
    __syncthreads();
  }

  int row0 = bm * 128 + wr * 64, col0 = bn * 128 + wc * 64;
#pragma unroll
  for (int mf = 0; mf < 4; ++mf)
#pragma unroll
    for (int j = 0; j < 4; ++j) {
      int row = row0 + mf * 16 + (lane >> 4) * 4 + j;
#pragma unroll
      for (int nf = 0; nf < 4; ++nf)
        out[(size_t)row * 1024 + col0 + nf * 16 + (lane & 15)] = acc[mf][nf][j];
    }
}

// ---------------- launch ----------------
extern "C" void kernel_launch(void* const* d_in, const int* in_sizes, int n_in,
                              void* d_out, int out_size, void* d_ws, size_t ws_size,
                              hipStream_t stream) {
  const float* x  = (const float*)d_in[0];
  const int* qpos = (const int*)d_in[1];
  const float* Wq = (const float*)d_in[2];
  const float* Wk = (const float*)d_in[3];
  const float* Wv = (const float*)d_in[4];
  const float* Wo = (const float*)d_in[5];
  float* out = (float*)d_out;

  char* ws = (char*)d_ws;
  _Float16* xh  = (_Float16*)(ws);                 // 8 MB  [4096][1024]
  _Float16* WT  = (_Float16*)(ws + 8388608);       // 3 MB  [1536][1024] (q,k,v stacked)
  _Float16* WoT = (_Float16*)(ws + 11534336);      // 2 MB  [1024][1024]
  _Float16* qhp = (_Float16*)(ws + 13631488);      // 8 MB  [B][HQ][S][D]
  _Float16* khp = (_Float16*)(ws + 22020096);      // 2 MB  [B][HK][S][D]
  _Float16* vhp = (_Float16*)(ws + 24117248);      // 2 MB  [B][HK][S][D]
  _Float16* ohp = (_Float16*)(ws + 26214400);      // 8 MB  [4096][1024]
  float2*   rtab = (float2*)(ws + 34603008);       // 1 MB  [4096][32]
  _Float16* vtp = (_Float16*)(ws + 35651584);      // 2 MB  [B][HK][D][S]

  cvt_x_kernel<<<4096, 256, 0, stream>>>(x, xh, 1048576);
  rope_tab_kernel<<<512, 256, 0, stream>>>(qpos, rtab);
  transpose_w_kernel<<<dim3(16, 16), 256, 0, stream>>>(Wq, WT, 1024, 0);
  transpose_w_kernel<<<dim3(4, 16), 256, 0, stream>>>(Wk, WT, 256, 1024);
  transpose_w_kernel<<<dim3(4, 16), 256, 0, stream>>>(Wv, WT, 256, 1280);
  transpose_w_kernel<<<dim3(16, 16), 256, 0, stream>>>(Wo, WoT, 1024, 0);
  gemm_qkv_rope<<<dim3(32, 12), 256, 0, stream>>>(xh, WT, rtab, qhp, khp, vhp);
  transpose_v_kernel<<<dim3(32, 8), 256, 0, stream>>>(vhp, vtp);
  attn_kernel<<<dim3(16, 32), 256, 0, stream>>>(qhp, khp, vtp, ohp);
  gemm_out<<<dim3(32, 8), 256, 0, stream>>>(ohp, WoT, out);
}